// Round 2
// baseline (404.897 us; speedup 1.0000x reference)
//
#include <hip/hip_runtime.h>

// Problem constants (from setup_inputs): B=64, C=3, H=W=512, patch 16x16,
// nearest-upsample scale = 512/16 = 32, widen buf = 16.
#define HH 512
#define WW 512
#define PH 16
#define PW 16
#define BATCH 64
#define CCH 3
#define W4 (WW / 4)          // 128 float4 per row
#define PLANE4 (HH * W4)     // 65536 float4 per (b,c) plane

typedef float f4 __attribute__((ext_vector_type(4)));

// Kernel 1: per-batch bbox of nonzero patch cells -> widened pixel rect.
// One block (256 threads) per batch; cell (r,c) = (tid>>4, tid&15).
// Matches reference argmax-of-all-false degenerate case: no nonzero cell
// => bbox = full image.
__global__ void bbox_kernel(const int* __restrict__ patch,
                            const int* __restrict__ widen_p,
                            int4* __restrict__ rects) {
    __shared__ int s_rmin, s_rmax, s_cmin, s_cmax;
    const int t = threadIdx.x;
    if (t == 0) { s_rmin = 1 << 30; s_rmax = -1; s_cmin = 1 << 30; s_cmax = -1; }
    __syncthreads();
    const int b = blockIdx.x;
    const int v = patch[b * (PH * PW) + t];
    if (v != 0) {
        const int r = t >> 4, c = t & 15;
        atomicMin(&s_rmin, r);
        atomicMax(&s_rmax, r);
        atomicMin(&s_cmin, c);
        atomicMax(&s_cmax, c);
    }
    __syncthreads();
    if (t == 0) {
        // degenerate (no nonzero): argmax(all-false)=0 on both ends
        // => h_min=0, h_max=H-1 => patch bbox = full grid
        const int rmin = (s_rmax < 0) ? 0 : s_rmin;
        const int rmax = (s_rmax < 0) ? (PH - 1) : s_rmax;
        const int cmin = (s_cmax < 0) ? 0 : s_cmin;
        const int cmax = (s_cmax < 0) ? (PW - 1) : s_cmax;
        const int wd = *widen_p;
        int hs = 32 * rmin - wd;            if (hs < 0) hs = 0;
        int he = 32 * rmax + 31 + wd + 1;   if (he > HH) he = HH;
        int ws = 32 * cmin - wd;            if (ws < 0) ws = 0;
        int we = 32 * cmax + 31 + wd + 1;   if (we > WW) we = WW;
        rects[b] = make_int4(hs, he, ws, we);
    }
}

// Kernel 2: branchless float4 select, 4 float4/thread.
// grid = (PLANE4/1024, C, B), block = 256.
// - b = blockIdx.z => rects[b] / *widen_p are wave-uniform (s_load).
// - pointer-select => exactly ONE global load per element, no divergence.
// - nontemporal: 603 MB working set > 256 MB L3, nothing is re-read.
__global__ __launch_bounds__(256) void apply_kernel(
        const f4* __restrict__ img,
        const f4* __restrict__ noise,
        const int* __restrict__ patch,
        const int* __restrict__ widen_p,
        const int4* __restrict__ rects,
        f4* __restrict__ out) {
    const int b    = blockIdx.z;
    const int bc   = b * CCH + blockIdx.y;
    const int base = bc * PLANE4 + blockIdx.x * 1024;   // fits in int (12.6M max)
    const int wd   = *widen_p;
    const int4 r   = rects[b];

#pragma unroll
    for (int j = 0; j < 4; ++j) {
        const int p = blockIdx.x * 1024 + j * 256 + threadIdx.x;  // plane f4 idx
        const int y = p >> 7;                // p / W4
        const int x = (p & (W4 - 1)) << 2;   // first pixel x of this float4
        bool inside;
        if (wd > 0) {
            // rect x-bounds are multiples of 16 => float4 never straddles
            inside = (y >= r.x) & (y < r.y) & (x >= r.z) & (x < r.w);
        } else {
            inside = patch[b * (PH * PW) + (y >> 5) * PW + (x >> 5)] != 0;
        }
        const f4* __restrict__ src = inside ? img : noise;
        const int i = base + j * 256 + (int)threadIdx.x;
        f4 v = __builtin_nontemporal_load(src + i);
        f4 n;
        n.x = fminf(fmaxf(v.x * 0.2f + 0.5f, 0.0f), 1.0f);
        n.y = fminf(fmaxf(v.y * 0.2f + 0.5f, 0.0f), 1.0f);
        n.z = fminf(fmaxf(v.z * 0.2f + 0.5f, 0.0f), 1.0f);
        n.w = fminf(fmaxf(v.w * 0.2f + 0.5f, 0.0f), 1.0f);
        f4 o = inside ? v : n;
        __builtin_nontemporal_store(o, out + i);
    }
}

extern "C" void kernel_launch(void* const* d_in, const int* in_sizes, int n_in,
                              void* d_out, int out_size, void* d_ws, size_t ws_size,
                              hipStream_t stream) {
    const float* img   = (const float*)d_in[0];   // [B,C,H,W] f32
    const int*   patch = (const int*)d_in[1];     // [B,16,16] i32
    const float* noise = (const float*)d_in[2];   // [B,C,H,W] f32
    const int*   widen = (const int*)d_in[3];     // scalar i32

    int4* rects = (int4*)d_ws;                    // 64 * 16 B = 1 KB

    bbox_kernel<<<BATCH, PH * PW, 0, stream>>>(patch, widen, rects);

    dim3 grid(PLANE4 / 1024, CCH, BATCH);         // (64, 3, 64) = 12288 blocks
    apply_kernel<<<grid, 256, 0, stream>>>((const f4*)img,
                                           (const f4*)noise,
                                           patch, widen, rects,
                                           (f4*)d_out);
}